// Round 5
// baseline (92.438 us; speedup 1.0000x reference)
//
#include <hip/hip_runtime.h>
#include <hip/hip_bf16.h>

// Problem constants
#define NA 32      // agents per graph
#define NACT 64    // actions
#define NIN 128    // in_dim
#define NOUT 128   // out_dim
#define NB 256     // graphs
// N = NB*NA = 8192 nodes.
// Inputs f32 (round-3 NaN proved bf16 decode breaks). Outputs f32:
//   obs_final [8192,32,192], then w_out [8192,32,1], flat-concatenated.

// ---------------------------------------------------------------------------
// Kernel A: per-graph  K = h@Wk+bk, Q = h@Wq+bq, scores = QK^T/sqrt(128),
// w = softmax over src j.  Writes w_out (f32).
// grid = 256 (one per graph), block = 1024 (16 waves).
// ---------------------------------------------------------------------------
__global__ __launch_bounds__(1024) void qk_softmax_kernel(
    const float* __restrict__ h,
    const float* __restrict__ Wk, const float* __restrict__ bk,
    const float* __restrict__ Wq, const float* __restrict__ bq,
    float* __restrict__ w_out)
{
    __shared__ float sh[NA][NIN];        // 16 KB
    __shared__ float sK[NA][NOUT + 4];
    __shared__ float sQ[NA][NOUT + 4];

    const int b   = blockIdx.x;
    const int tid = threadIdx.x;

    // stage h tile (32x128 f32 = 1024 float4)
    {
        const float4* src = reinterpret_cast<const float4*>(h + (size_t)b * NA * NIN);
        reinterpret_cast<float4*>(&sh[0][0])[tid] = src[tid];
    }
    __syncthreads();

    // ---- projection: thread (tx = out-dim 0..127, ty = node-group 0..7), 4 nodes
    const int tx = tid & 127;
    const int ty = tid >> 7;
    float ak[4], aq[4];
    {
        const float bkv = bk[tx];
        const float bqv = bq[tx];
#pragma unroll
        for (int s = 0; s < 4; ++s) { ak[s] = bkv; aq[s] = bqv; }
    }
    for (int r = 0; r < NIN; r += 4) {
        const float wk0 = Wk[(r + 0) * NOUT + tx];
        const float wk1 = Wk[(r + 1) * NOUT + tx];
        const float wk2 = Wk[(r + 2) * NOUT + tx];
        const float wk3 = Wk[(r + 3) * NOUT + tx];
        const float wq0 = Wq[(r + 0) * NOUT + tx];
        const float wq1 = Wq[(r + 1) * NOUT + tx];
        const float wq2 = Wq[(r + 2) * NOUT + tx];
        const float wq3 = Wq[(r + 3) * NOUT + tx];
#pragma unroll
        for (int s = 0; s < 4; ++s) {
            const int n = ty * 4 + s;
            const float4 hv = *reinterpret_cast<const float4*>(&sh[n][r]);
            ak[s] = fmaf(hv.x, wk0, fmaf(hv.y, wk1, fmaf(hv.z, wk2, fmaf(hv.w, wk3, ak[s]))));
            aq[s] = fmaf(hv.x, wq0, fmaf(hv.y, wq1, fmaf(hv.z, wq2, fmaf(hv.w, wq3, aq[s]))));
        }
    }
#pragma unroll
    for (int s = 0; s < 4; ++s) {
        const int n = ty * 4 + s;
        sK[n][tx] = ak[s];
        sQ[n][tx] = aq[s];
    }
    __syncthreads();

    // ---- scores + softmax: thread (i = tid>>5 dst, j = tid&31 src)
    const int i = tid >> 5;
    const int j = tid & 31;
    float sc = 0.f;
    for (int r = 0; r < NOUT; r += 4) {
        const float4 qv = *reinterpret_cast<const float4*>(&sQ[i][r]);
        const float4 kv = *reinterpret_cast<const float4*>(&sK[j][r]);
        sc = fmaf(qv.x, kv.x, fmaf(qv.y, kv.y, fmaf(qv.z, kv.z, fmaf(qv.w, kv.w, sc))));
    }
    sc *= 0.08838834764831845f;  // 1/sqrt(128)

    // softmax across the 32-lane j group (xor offsets <=16 stay in each half-wave)
    float m = sc;
#pragma unroll
    for (int off = 16; off >= 1; off >>= 1) m = fmaxf(m, __shfl_xor(m, off));
    const float e = __expf(sc - m);
    float ssum = e;
#pragma unroll
    for (int off = 16; off >= 1; off >>= 1) ssum += __shfl_xor(ssum, off);
    const float w = e / ssum;

    w_out[(size_t)b * (NA * NA) + tid] = w;   // (b*32+i)*32 + j
}

// ---------------------------------------------------------------------------
// Kernel B: per (b, i-dst): z_mix + concat(obs) -> obs_final (f32).
// Reads w (f32) straight from the w_out region of d_out.
// grid = 8192, block = 256 (4 waves).
// ---------------------------------------------------------------------------
__global__ __launch_bounds__(256) void mix_kernel(
    const float* __restrict__ policies, const float* __restrict__ actions,
    const float* __restrict__ obs, const float* __restrict__ noise,
    const float* __restrict__ w_in, float* __restrict__ out)
{
    __shared__ float spi[NA][NACT];   // pi[j][c]
    __shared__ float sact[NA][NACT];  // act[j][c]
    __shared__ float snz[NA][NACT];   // noise[b,i,j,c]
    __shared__ float szx[NA][NACT];   // z_mix[t][c]
    __shared__ float spart[4][NACT];
    __shared__ float swr[NA];
    __shared__ float szm[NACT];

    const int blk = blockIdx.x;       // = b*32 + i
    const int b   = blk >> 5;
    const int tid = threadIdx.x;

    // stage pi/act (per graph) and noise (per (b,i)): 2048 f32 each = 512 float4
    {
        const float4* ps = reinterpret_cast<const float4*>(policies + (size_t)b * NA * NACT);
        const float4* as = reinterpret_cast<const float4*>(actions  + (size_t)b * NA * NACT);
        const float4* ns = reinterpret_cast<const float4*>(noise    + (size_t)blk * NA * NACT);
        float4* pd = reinterpret_cast<float4*>(&spi[0][0]);
        float4* ad = reinterpret_cast<float4*>(&sact[0][0]);
        float4* nd = reinterpret_cast<float4*>(&snz[0][0]);
        pd[tid] = ps[tid]; pd[tid + 256] = ps[tid + 256];
        ad[tid] = as[tid]; ad[tid + 256] = as[tid + 256];
        nd[tid] = ns[tid]; nd[tid + 256] = ns[tid + 256];
        if (tid < NA) swr[tid] = w_in[(size_t)blk * NA + tid];
    }
    __syncthreads();

    const int c = tid & 63;
    const int g = tid >> 6;  // 0..3

    // pass 1: partial sums over j of z = w*(act-pi)+pi+noise
    float p = 0.f;
#pragma unroll
    for (int u = 0; u < 8; ++u) {
        const int jj = g * 8 + u;
        p += fmaf(swr[jj], sact[jj][c] - spi[jj][c], spi[jj][c]) + snz[jj][c];
    }
    spart[g][c] = p;
    __syncthreads();
    if (tid < NACT) {
        szm[tid] = (spart[0][tid] + spart[1][tid] + spart[2][tid] + spart[3][tid]) * (1.0f / NA);
    }
    __syncthreads();

    // pass 2: z_mix[t][c] = zmean[c] + (pi[t][c] - z[t][c]) / A
    const float zm = szm[c];
#pragma unroll
    for (int u = 0; u < 8; ++u) {
        const int t = g * 8 + u;
        const float z = fmaf(swr[t], sact[t][c] - spi[t][c], spi[t][c]) + snz[t][c];
        szx[t][c] = zm + (spi[t][c] - z) * (1.0f / NA);
    }
    __syncthreads();

    // output row blk: 32 slots t x (128 obs | 64 z_mix) f32 = 1536 float4.
    // obs part: exact float4 copy of obs_proc row t of graph b.
    const float* obs_g = obs + (size_t)b * NA * NIN;
    float4* out4 = reinterpret_cast<float4*>(out) + (size_t)blk * 1536;
#pragma unroll
    for (int k = 0; k < 6; ++k) {
        const int mm = tid + 256 * k;   // 0..1535
        const int t  = mm / 48;
        const int n  = mm % 48;
        if (n < 32) {
            out4[mm] = *reinterpret_cast<const float4*>(obs_g + t * NIN + n * 4);
        } else {
            const int cc = (n - 32) * 4;
            out4[mm] = *reinterpret_cast<const float4*>(&szx[t][cc]);
        }
    }
}

extern "C" void kernel_launch(void* const* d_in, const int* in_sizes, int n_in,
                              void* d_out, int out_size, void* d_ws, size_t ws_size,
                              hipStream_t stream) {
    const float* h        = (const float*)d_in[0];
    const float* policies = (const float*)d_in[1];
    const float* actions  = (const float*)d_in[2];
    const float* obs_proc = (const float*)d_in[3];
    const float* noise    = (const float*)d_in[4];
    const float* Wk       = (const float*)d_in[5];
    const float* bk       = (const float*)d_in[6];
    const float* Wq       = (const float*)d_in[7];
    const float* bq       = (const float*)d_in[8];

    float* out = (float*)d_out;
    float* obs_final = out;                                      // [8192,32,192]
    float* w_out = out + (size_t)NB * NA * NA * (NIN + NACT);    // [8192,32,1]

    qk_softmax_kernel<<<NB, 1024, 0, stream>>>(h, Wk, bk, Wq, bq, w_out);
    mix_kernel<<<NB * NA, 256, 0, stream>>>(policies, actions, obs_proc, noise,
                                            w_out, obs_final);
}